// Round 2
// baseline (105.360 us; speedup 1.0000x reference)
//
#include <hip/hip_runtime.h>

#define NB 32
#define NS 2048
#define NH 1024
#define WIN 15   // exp(score-lse-0.5*d^2) underflows to exact 0.0f beyond |d|>15

// ---------------- kp: partial v. vp[ds][b][h] = sum_{d in slice ds} dec[b,d]*Wa[d,h]
// grid = 8 dslices * 4 htiles * 32 b = 1024 blocks (b fastest -> Wa tile L2 reuse)
__global__ __launch_bounds__(256) void kp_vpart(const float* __restrict__ dec,
                                                const float* __restrict__ Wa,
                                                float* __restrict__ vp,
                                                double* __restrict__ denomD) {
    int blk = blockIdx.x;
    int b   = blk & 31;
    int ht  = (blk >> 5) & 3;
    int ds  = blk >> 7;
    if (blk == 0 && threadIdx.x < NB) denomD[threadIdx.x] = 0.0;  // k2 atomics come later in stream

    int h = ht * 256 + threadIdx.x;
    const float* decb = dec + b * NH + ds * 128;
    const float* wa   = Wa + (size_t)(ds * 128) * NH + h;
    float acc = 0.f;
#pragma unroll 8
    for (int d = 0; d < 128; ++d)
        acc = fmaf(decb[d], wa[(size_t)d * NH], acc);
    vp[(ds * NB + b) * NH + h] = acc;
}

// ---------------- kr: v[b,h] = sum_ds vp[ds][b][h]
__global__ __launch_bounds__(256) void kr_vred(const float* __restrict__ vp,
                                               float* __restrict__ v) {
    int idx = blockIdx.x * 256 + threadIdx.x;   // 0..NB*NH-1
    float acc = 0.f;
#pragma unroll
    for (int ds = 0; ds < 8; ++ds) acc += vp[ds * (NB * NH) + idx];
    v[idx] = acc;
}

// ---------------- k2: scores[b,s] = enc[b,s,:].v[b,:]; denomD[b] += sum exp(score)
// 8 rows/block (2 rows/wave), 8192 blocks. Block 0 also zeroes ctx for k3's atomics.
__global__ __launch_bounds__(256) void k2_scores(const float* __restrict__ enc,
                                                 const float* __restrict__ v,
                                                 float* __restrict__ scores,
                                                 double* __restrict__ denomD,
                                                 float* __restrict__ ctx) {
    __shared__ float vs[NH];
    __shared__ float rowsc[8];
    int row0 = blockIdx.x * 8;
    int b = row0 >> 11;

    if (blockIdx.x == 0) {
        for (int i = threadIdx.x; i < NB * NH; i += 256) ctx[i] = 0.f;
    }

    ((float4*)vs)[threadIdx.x] = ((const float4*)(v + b * NH))[threadIdx.x];
    __syncthreads();

    int wid = threadIdx.x >> 6, lane = threadIdx.x & 63;
    int r0 = row0 + wid * 2;
    const float4* e0 = (const float4*)(enc + (size_t)r0 * NH);
    const float4* e1 = e0 + (NH / 4);
    const float4* vv = (const float4*)vs;

    float acc0 = 0.f, acc1 = 0.f;
#pragma unroll
    for (int k = 0; k < 4; ++k) {
        float4 a0 = e0[k * 64 + lane];
        float4 a1 = e1[k * 64 + lane];
        float4 bb = vv[k * 64 + lane];
        acc0 = fmaf(a0.x, bb.x, acc0); acc0 = fmaf(a0.y, bb.y, acc0);
        acc0 = fmaf(a0.z, bb.z, acc0); acc0 = fmaf(a0.w, bb.w, acc0);
        acc1 = fmaf(a1.x, bb.x, acc1); acc1 = fmaf(a1.y, bb.y, acc1);
        acc1 = fmaf(a1.z, bb.z, acc1); acc1 = fmaf(a1.w, bb.w, acc1);
    }
#pragma unroll
    for (int off = 32; off >= 1; off >>= 1) {
        acc0 += __shfl_xor(acc0, off, 64);
        acc1 += __shfl_xor(acc1, off, 64);
    }
    if (lane == 0) {
        scores[r0]     = acc0;
        scores[r0 + 1] = acc1;
        rowsc[wid * 2]     = acc0;
        rowsc[wid * 2 + 1] = acc1;
    }
    __syncthreads();
    if (threadIdx.x == 0) {
        double sum = 0.0;
#pragma unroll
        for (int i = 0; i < 8; ++i) sum += exp((double)rowsc[i]);
        atomicAdd(&denomD[b], sum);
    }
}

// ---------------- k3: attn[b,s] = exp(score - lse - 0.5 d^2); windowed ctx via atomics
// grid = 32 b * 8 s-chunks = 256 blocks
__global__ __launch_bounds__(256) void k3_out(const float* __restrict__ enc,
                                              const float* __restrict__ scores,
                                              const int* __restrict__ ts,
                                              const double* __restrict__ denomD,
                                              float* __restrict__ ctx,
                                              float* __restrict__ attn) {
    int b = blockIdx.x >> 3;
    int c = blockIdx.x & 7;
    int t = threadIdx.x;

    float lse = (float)log(denomD[b]);
    int p = ts[b];
    float pf = (float)p;

    int s = c * 256 + t;
    float sc = scores[b * NS + s];
    float d = (float)s - pf;
    attn[b * NS + s] = expf(sc - lse - 0.5f * d * d);

    int w0 = max(0, p - WIN), w1 = min(NS - 1, p + WIN);
    int r0 = max(w0, c * 256), r1 = min(w1, c * 256 + 255);
    if (r0 <= r1) {
        const float* sb = scores + b * NS;
        float a0 = 0.f, a1 = 0.f, a2 = 0.f, a3 = 0.f;
        for (int r = r0; r <= r1; ++r) {
            float dr = (float)r - pf;
            float w = expf(sb[r] - lse - 0.5f * dr * dr);
            const float* er = enc + ((size_t)b * NS + r) * NH;
            a0 = fmaf(w, er[t],       a0);
            a1 = fmaf(w, er[t + 256], a1);
            a2 = fmaf(w, er[t + 512], a2);
            a3 = fmaf(w, er[t + 768], a3);
        }
        atomicAdd(&ctx[b * NH + t],       a0);
        atomicAdd(&ctx[b * NH + t + 256], a1);
        atomicAdd(&ctx[b * NH + t + 512], a2);
        atomicAdd(&ctx[b * NH + t + 768], a3);
    }
}

extern "C" void kernel_launch(void* const* d_in, const int* in_sizes, int n_in,
                              void* d_out, int out_size, void* d_ws, size_t ws_size,
                              hipStream_t stream) {
    const float* enc  = (const float*)d_in[0];   // [B,S,H]
    const float* dec  = (const float*)d_in[1];   // [B,H]
    const int*   ts   = (const int*)d_in[2];     // [B]
    const float* Wa_w = (const float*)d_in[3];   // [H,H]
    // d_in[4] = Wa_b: uniform shift of scores per b -> softmax-invariant, dropped.

    float* out  = (float*)d_out;
    float* ctx  = out;             // [B,H]
    float* attn = out + NB * NH;   // [B,S]

    float*  vp     = (float*)d_ws;                       // 8*NB*NH
    float*  v      = vp + 8 * NB * NH;                   // NB*NH
    float*  scores = v + NB * NH;                        // NB*NS
    double* denomD = (double*)(scores + NB * NS);        // NB (8B aligned: offsets are all /8)

    kp_vpart <<<1024,        256, 0, stream>>>(dec, Wa_w, vp, denomD);
    kr_vred  <<<NB * NH/256, 256, 0, stream>>>(vp, v);
    k2_scores<<<NB * NS / 8, 256, 0, stream>>>(enc, v, scores, denomD, ctx);
    k3_out   <<<NB * 8,      256, 0, stream>>>(enc, scores, ts, denomD, ctx, attn);
}